// Round 7
// baseline (466.729 us; speedup 1.0000x reference)
//
#include <hip/hip_runtime.h>
#include <math.h>

// EncoderBlock: B=8, N=1024, EMB=768, HEADS=8, DHEAD=96
// R7: GEMM K-loop -> AITER-style async pipeline: BK=32, 3 LDS buffers,
//     depth-2 global_load_lds prefetch, per-iter `s_waitcnt vmcnt(4)` (oldest
//     stage only — NEVER vmcnt(0) mid-loop) + raw s_barrier (no compiler
//     drain). Removes the block-wide vmcnt(0) convoy point that left R6 at
//     MfmaUtil 18% with ~800cy exposed HBM latency per iteration.
//     LDS 48 KB -> 3 blocks/CU; XOR-period-8 slot swizzle keeps ds_read_b128
//     at 2-way banks (free) with global-side inverse perm (same 64B line).

typedef __bf16 bf16_t;
typedef __bf16 bf16x4 __attribute__((ext_vector_type(4)));
typedef __bf16 bf16x8 __attribute__((ext_vector_type(8)));
typedef float f32x4 __attribute__((ext_vector_type(4)));

#define EMB   768
#define HEADS 8
#define DHEAD 96
#define BATCH 8
#define SEQ   1024
#define ROWS  (BATCH * SEQ)   // 8192

__device__ __forceinline__ void load16_lds(const bf16_t* g, bf16_t* l) {
    __builtin_amdgcn_global_load_lds(
        (__attribute__((address_space(1))) unsigned int*)g,
        (__attribute__((address_space(3))) unsigned int*)l,
        16, 0, 0);
}

// ---------------------------------------------------------------- conversions

__global__ void cvt_bf16_kernel(const float* __restrict__ in, bf16_t* __restrict__ out, int n) {
    int stride = gridDim.x * blockDim.x;
    for (int i = blockIdx.x * blockDim.x + threadIdx.x; i < n; i += stride)
        out[i] = (bf16_t)in[i];
}

// in: [K][N] fp32 row-major  ->  out: [N][K] bf16 row-major (B^T for GEMMs)
__global__ void transpose_cvt_kernel(const float* __restrict__ in, bf16_t* __restrict__ out,
                                     int K, int N) {
    __shared__ float t[32][33];
    int n0 = blockIdx.x * 32, k0 = blockIdx.y * 32;
    int tx = threadIdx.x, ty0 = threadIdx.y;  // block (32,8)
#pragma unroll
    for (int i = 0; i < 4; i++) {
        int ty = ty0 + 8 * i;
        t[ty][tx] = in[(size_t)(k0 + ty) * N + n0 + tx];
    }
    __syncthreads();
#pragma unroll
    for (int i = 0; i < 4; i++) {
        int ty = ty0 + 8 * i;
        out[(size_t)(n0 + ty) * K + k0 + tx] = (bf16_t)t[tx][ty];
    }
}

// ---------------------------------------------------------------- GEMM (bf16 MFMA)
// C[M,N] = A[M,K] @ BT[N,K]^T + bias, 128x128 tile, BK=32, 256 thr, 4 waves 2x2.
// Async 3-stage pipeline; swizzle: LDS slot s of row R holds global k-unit
// j = (s - (R>>1)) & 3  (16B units, 4 per row).

enum { EPI_QKVR = 0, EPI_PROJ = 1, EPI_GELU = 2, EPI_FF2 = 3 };

template <int EPI, int KDIM>
__global__ __launch_bounds__(256) void gemm_kernel(
    const bf16_t* __restrict__ A,    // [M,KDIM]
    const bf16_t* __restrict__ BT,   // [N,KDIM]
    const float* __restrict__ bias,  // [N]
    bf16_t* __restrict__ qo, bf16_t* __restrict__ ko,
    bf16_t* __restrict__ vTo, bf16_t* __restrict__ ro,   // EPI_QKVR outputs
    const float* __restrict__ resid,                     // EPI_PROJ / EPI_FF2 residual
    float* __restrict__ outf,                            // EPI_PROJ / EPI_FF2 fp32 out
    bf16_t* __restrict__ outb)                           // EPI_GELU bf16 out
{
    __shared__ __align__(16) bf16_t As[3][128 * 32];
    __shared__ __align__(16) bf16_t Bs[3][128 * 32];

    const int tid  = threadIdx.x;
    const int wave = tid >> 6, lane = tid & 63;
    const int quad = lane >> 4, col16 = lane & 15;
    const int m0 = blockIdx.y * 128, n0 = blockIdx.x * 128;
    const int wrow = (wave >> 1) * 64, wcol = (wave & 1) * 64;

    f32x4 acc[4][4] = {};

    // staging map: 512 16B-units per tile (128 rows x 4 slots); 2 units/thread.
    // unit u -> row rr=u>>2, slot s=u&3, global k-unit j=(s-(rr>>1))&3.
    const int c0 = tid, c1 = tid + 256;
    const int rr0 = c0 >> 2, j0 = ((c0 & 3) + 4 - ((rr0 >> 1) & 3)) & 3;
    const int rr1 = c1 >> 2, j1 = ((c1 & 3) + 4 - ((rr1 >> 1) & 3)) & 3;
    const size_t ga0 = (size_t)(m0 + rr0) * KDIM + j0 * 8;
    const size_t ga1 = (size_t)(m0 + rr1) * KDIM + j1 * 8;
    const size_t gb0 = (size_t)(n0 + rr0) * KDIM + j0 * 8;
    const size_t gb1 = (size_t)(n0 + rr1) * KDIM + j1 * 8;

    constexpr int NK = KDIM / 32;

    // prologue: prefetch stages 0 and 1 (8 loads/thread outstanding)
#pragma unroll
    for (int st = 0; st < 2; st++) {
        load16_lds(A + ga0 + st * 32, As[st] + c0 * 8);
        load16_lds(A + ga1 + st * 32, As[st] + c1 * 8);
        load16_lds(BT + gb0 + st * 32, Bs[st] + c0 * 8);
        load16_lds(BT + gb1 + st * 32, Bs[st] + c1 * 8);
    }

    for (int kk = 0; kk < NK; kk++) {
        // wait ONLY the oldest stage (kk); stage kk+1 stays in flight.
        if (kk + 1 < NK) asm volatile("s_waitcnt vmcnt(4)" ::: "memory");
        else             asm volatile("s_waitcnt vmcnt(0)" ::: "memory");
        // raw barrier: no compiler-inserted vmcnt(0) drain.
        asm volatile("s_barrier" ::: "memory");
        if (kk + 2 < NK) {
            const int k2 = (kk + 2) * 32;
            bf16_t* Ad = As[(kk + 2) % 3];
            bf16_t* Bd = Bs[(kk + 2) % 3];
            load16_lds(A + ga0 + k2, Ad + c0 * 8);
            load16_lds(A + ga1 + k2, Ad + c1 * 8);
            load16_lds(BT + gb0 + k2, Bd + c0 * 8);
            load16_lds(BT + gb1 + k2, Bd + c1 * 8);
        }
        const bf16_t* Ar = As[kk % 3];
        const bf16_t* Br = Bs[kk % 3];
        bf16x8 af[4], bfr[4];
#pragma unroll
        for (int t = 0; t < 4; t++) {
            const int R = wrow + t * 16 + col16;
            af[t] = *reinterpret_cast<const bf16x8*>(Ar + R * 32 + ((quad + (R >> 1)) & 3) * 8);
        }
#pragma unroll
        for (int t = 0; t < 4; t++) {
            const int R = wcol + t * 16 + col16;
            bfr[t] = *reinterpret_cast<const bf16x8*>(Br + R * 32 + ((quad + (R >> 1)) & 3) * 8);
        }
#pragma unroll
        for (int tr = 0; tr < 4; tr++)
#pragma unroll
            for (int tc = 0; tc < 4; tc++)
                acc[tr][tc] = __builtin_amdgcn_mfma_f32_16x16x32_bf16(af[tr], bfr[tc], acc[tr][tc], 0, 0, 0);
    }

#pragma unroll
    for (int tr = 0; tr < 4; tr++) {
#pragma unroll
        for (int tc = 0; tc < 4; tc++) {
#pragma unroll
            for (int rg = 0; rg < 4; rg++) {
                const int row  = m0 + wrow + tr * 16 + quad * 4 + rg;
                const int colg = n0 + wcol + tc * 16 + col16;
                float v = acc[tr][tc][rg] + bias[colg];
                if (EPI == EPI_QKVR) {
                    const int which = colg & 3, hd = colg >> 2;
                    const int head = hd / DHEAD, dd = hd % DHEAD;
                    const int b = row >> 10, nn = row & 1023;
                    const int bh = b * HEADS + head;
                    if (which == 0)      qo[((size_t)bh * SEQ + nn) * DHEAD + dd]   = (bf16_t)v;
                    else if (which == 1) ko[((size_t)bh * SEQ + nn) * DHEAD + dd]   = (bf16_t)v;
                    else if (which == 2) vTo[((size_t)bh * DHEAD + dd) * SEQ + nn]  = (bf16_t)v;  // V^T
                    else                 ro[((size_t)bh * SEQ + nn) * DHEAD + dd]   = (bf16_t)v;
                } else if (EPI == EPI_PROJ || EPI == EPI_FF2) {
                    outf[(size_t)row * EMB + colg] = v + resid[(size_t)row * EMB + colg];
                } else {  // EPI_GELU, exact gelu
                    float g = 0.5f * v * (1.0f + erff(v * 0.70710678118654752f));
                    outb[(size_t)row * 3072 + colg] = (bf16_t)g;
                }
            }
        }
    }
}

// ---------------------------------------------------------------- attention
// (unchanged from R6 — off the critical path now)

__global__ __launch_bounds__(256) void attn_kernel(
    const bf16_t* __restrict__ q, const bf16_t* __restrict__ k,
    const bf16_t* __restrict__ vT, const bf16_t* __restrict__ r,
    bf16_t* __restrict__ attn_out)
{
    __shared__ __align__(16) bf16_t Ks[64 * 96];    // [key][dim]
    __shared__ __align__(16) bf16_t Vs[96 * 64];    // [feat][16B-unit swizzled by feat&7]
    __shared__ __align__(16) bf16_t P[4][16 * 72];  // wave-private P (barriers protect reuse)

    const int tid = threadIdx.x, wave = tid >> 6, lane = tid & 63;
    const int quad = lane >> 4, col = lane & 15;
    const int bh = blockIdx.x & 63, qb = blockIdx.x >> 6;
    const int n0 = qb * 64 + wave * 16;
    const bf16_t* qp = q  + (size_t)bh * SEQ * DHEAD;
    const bf16_t* kb = k  + (size_t)bh * SEQ * DHEAD;
    const bf16_t* vb = vT + (size_t)bh * DHEAD * SEQ;
    bf16_t* Pw = P[wave];

    bf16x8 qf[3];  // Q as B-operand: B[k=dim][n=q-row]
#pragma unroll
    for (int ks = 0; ks < 3; ks++)
        qf[ks] = *reinterpret_cast<const bf16x8*>(qp + (size_t)(n0 + col) * DHEAD + ks * 32 + quad * 8);

    // staging unit ids (16B units): K has 64*12=768, V has 96*8=768
    const int u0 = tid, u1 = tid + 256, u2 = tid + 512;
    const int vf0 = u0 >> 3, vp0 = (u0 & 7) ^ (vf0 & 7);
    const int vf1 = u1 >> 3, vp1 = (u1 & 7) ^ (vf1 & 7);
    const int vf2 = u2 >> 3, vp2 = (u2 & 7) ^ (vf2 & 7);

    f32x4 O[6] = {};
    float lsum = 0.f;  // per-lane partial row-sum for q-row `col`

    for (int ch = 0; ch < SEQ / 64; ch++) {
        const int kc0 = ch * 64;
        __syncthreads();  // all waves done reading Ks/Vs of previous chunk
        const bf16_t* ksrc = kb + (size_t)kc0 * DHEAD;  // 64 keys x 96 dims, contiguous
        load16_lds(ksrc + u0 * 8, Ks + u0 * 8);
        load16_lds(ksrc + u1 * 8, Ks + u1 * 8);
        load16_lds(ksrc + u2 * 8, Ks + u2 * 8);
        load16_lds(vb + (size_t)vf0 * SEQ + kc0 + vp0 * 8, Vs + u0 * 8);
        load16_lds(vb + (size_t)vf1 * SEQ + kc0 + vp1 * 8, Vs + u1 * 8);
        load16_lds(vb + (size_t)vf2 * SEQ + kc0 + vp2 * 8, Vs + u2 * 8);
        __syncthreads();  // compiler drains vmcnt before barrier: tiles ready

        f32x4 s[4] = {};
#pragma unroll
        for (int ks = 0; ks < 3; ks++) {  // K as A-operand: A[m=key][k=dim]
#pragma unroll
            for (int h = 0; h < 4; h++) {
                bf16x8 kf = *reinterpret_cast<const bf16x8*>(Ks + (h * 16 + col) * DHEAD + ks * 32 + quad * 8);
                s[h] = __builtin_amdgcn_mfma_f32_16x16x32_bf16(kf, qf[ks], s[h], 0, 0, 0);
            }
        }
        // S^T C-layout: lane holds keys h*16+quad*4+rg for q-row `col`
#pragma unroll
        for (int h = 0; h < 4; h++) {
            bf16x4 w;
#pragma unroll
            for (int rg = 0; rg < 4; rg++) {
                const float e = __expf(s[h][rg]);
                lsum += e;
                w[rg] = (bf16_t)e;
            }
            *reinterpret_cast<bf16x4*>(Pw + col * 72 + h * 16 + quad * 4) = w;
        }
        // A-operand read back: A[m=q-row=col][k=key]
        bf16x8 af0 = *reinterpret_cast<const bf16x8*>(Pw + col * 72 + quad * 8);
        bf16x8 af1 = *reinterpret_cast<const bf16x8*>(Pw + col * 72 + 32 + quad * 8);
#pragma unroll
        for (int tc = 0; tc < 6; tc++) {  // V as B-operand: B[k=key][n=feat]
            const int feat = tc * 16 + col;
            bf16x8 bv0 = *reinterpret_cast<const bf16x8*>(Vs + feat * 64 + ((quad)     ^ (col & 7)) * 8);
            bf16x8 bv1 = *reinterpret_cast<const bf16x8*>(Vs + feat * 64 + ((4 + quad) ^ (col & 7)) * 8);
            O[tc] = __builtin_amdgcn_mfma_f32_16x16x32_bf16(af0, bv0, O[tc], 0, 0, 0);
            O[tc] = __builtin_amdgcn_mfma_f32_16x16x32_bf16(af1, bv1, O[tc], 0, 0, 0);
        }
    }

    // finalize row sums: reduce over quads (lanes sharing `col`)
    lsum += __shfl_xor(lsum, 16);
    lsum += __shfl_xor(lsum, 32);

    const float inv_sqrt_emb = 0.036084391824351615f;  // 1/sqrt(768)
    const int b = bh >> 3, h = bh & 7;
#pragma unroll
    for (int rg = 0; rg < 4; rg++) {
        const int nrow = quad * 4 + rg;
        const float lr = __shfl(lsum, nrow);  // lane nrow holds q-row nrow's sum
        const float scale = inv_sqrt_emb / lr;
        const int n = n0 + nrow;
#pragma unroll
        for (int tc = 0; tc < 6; tc++) {
            const int feat = tc * 16 + col;
            const float rv = (float)r[((size_t)bh * SEQ + n) * DHEAD + feat];
            attn_out[((size_t)(b * SEQ + n)) * EMB + h * DHEAD + feat] = (bf16_t)(O[tc][rg] * scale * rv);
        }
    }
}

// ---------------------------------------------------------------- LayerNorm (row=768)

__global__ __launch_bounds__(256) void ln_kernel(
    const float* __restrict__ in, const float* __restrict__ g, const float* __restrict__ b,
    float* __restrict__ y, bf16_t* __restrict__ yb)
{
    const int row = blockIdx.x * 4 + (threadIdx.x >> 6);
    const int lane = threadIdx.x & 63;
    const float* rp = in + (size_t)row * EMB;
    float v[12];
    float sum = 0.f;
#pragma unroll
    for (int i = 0; i < 12; i++) { v[i] = rp[lane + i * 64]; sum += v[i]; }
#pragma unroll
    for (int off = 32; off; off >>= 1) sum += __shfl_xor(sum, off);
    const float mean = sum * (1.0f / 768.0f);
    float s2 = 0.f;
#pragma unroll
    for (int i = 0; i < 12; i++) { float d = v[i] - mean; s2 += d * d; }
#pragma unroll
    for (int off = 32; off; off >>= 1) s2 += __shfl_xor(s2, off);
    const float inv = rsqrtf(s2 * (1.0f / 768.0f) + 1e-5f);
#pragma unroll
    for (int i = 0; i < 12; i++) {
        const int c = lane + i * 64;
        const float o = (v[i] - mean) * inv * g[c] + b[c];
        y[(size_t)row * EMB + c] = o;
        if (yb) yb[(size_t)row * EMB + c] = (bf16_t)o;
    }
}

// ---------------------------------------------------------------- launch

extern "C" void kernel_launch(void* const* d_in, const int* in_sizes, int n_in,
                              void* d_out, int out_size, void* d_ws, size_t ws_size,
                              hipStream_t stream)
{
    const float* x      = (const float*)d_in[0];
    const float* w_qkvr = (const float*)d_in[1];
    const float* b_qkvr = (const float*)d_in[2];
    const float* w_proj = (const float*)d_in[3];
    const float* b_proj = (const float*)d_in[4];
    const float* ln1_g  = (const float*)d_in[5];
    const float* ln1_b  = (const float*)d_in[6];
    const float* w_ff1  = (const float*)d_in[7];
    const float* b_ff1  = (const float*)d_in[8];
    const float* w_ff2  = (const float*)d_in[9];
    const float* b_ff2  = (const float*)d_in[10];
    const float* ln2_g  = (const float*)d_in[11];
    const float* ln2_b  = (const float*)d_in[12];
    float* out = (float*)d_out;

    char* ws = (char*)d_ws;
    size_t off = 0;
    auto alloc = [&](size_t bytes) {
        char* p = ws + off;
        off += (bytes + 255) & ~(size_t)255;
        return (void*)p;
    };
    const size_t ACT = (size_t)ROWS * EMB;  // 6291456
    bf16_t* xb      = (bf16_t*)alloc(ACT * 2);
    bf16_t* wqkvrT  = (bf16_t*)alloc((size_t)3072 * 768 * 2);
    bf16_t* wprojT  = (bf16_t*)alloc((size_t)768 * 768 * 2);
    bf16_t* wff1T   = (bf16_t*)alloc((size_t)3072 * 768 * 2);
    bf16_t* wff2T   = (bf16_t*)alloc((size_t)768 * 3072 * 2);
    bf16_t* qbuf    = (bf16_t*)alloc(ACT * 2);
    bf16_t* kbuf    = (bf16_t*)alloc(ACT * 2);
    bf16_t* vTbuf   = (bf16_t*)alloc(ACT * 2);
    bf16_t* rbuf    = (bf16_t*)alloc(ACT * 2);
    bf16_t* attn_o  = (bf16_t*)alloc(ACT * 2);
    float*  x1f     = (float*)alloc(ACT * 4);
    bf16_t* x1b     = (bf16_t*)alloc(ACT * 2);
    bf16_t* ff1     = (bf16_t*)alloc((size_t)ROWS * 3072 * 2);
    float*  res     = out;  // d_out doubles as fp32 residual scratch

    dim3 tb32(32, 8);

    cvt_bf16_kernel<<<2048, 256, 0, stream>>>(x, xb, (int)ACT);
    transpose_cvt_kernel<<<dim3(3072 / 32, 768 / 32), tb32, 0, stream>>>(w_qkvr, wqkvrT, 768, 3072);
    transpose_cvt_kernel<<<dim3(768 / 32, 768 / 32), tb32, 0, stream>>>(w_proj, wprojT, 768, 768);
    transpose_cvt_kernel<<<dim3(3072 / 32, 768 / 32), tb32, 0, stream>>>(w_ff1, wff1T, 768, 3072);
    transpose_cvt_kernel<<<dim3(768 / 32, 3072 / 32), tb32, 0, stream>>>(w_ff2, wff2T, 3072, 768);

    gemm_kernel<EPI_QKVR, 768><<<dim3(24, 64), 256, 0, stream>>>(
        xb, wqkvrT, b_qkvr, qbuf, kbuf, vTbuf, rbuf, nullptr, nullptr, nullptr);

    attn_kernel<<<dim3(SEQ / 64 * BATCH * HEADS), 256, 0, stream>>>(qbuf, kbuf, vTbuf, rbuf, attn_o);

    gemm_kernel<EPI_PROJ, 768><<<dim3(6, 64), 256, 0, stream>>>(
        attn_o, wprojT, b_proj, nullptr, nullptr, nullptr, nullptr, x, res, nullptr);
    ln_kernel<<<2048, 256, 0, stream>>>(res, ln1_g, ln1_b, x1f, x1b);

    gemm_kernel<EPI_GELU, 768><<<dim3(24, 64), 256, 0, stream>>>(
        x1b, wff1T, b_ff1, nullptr, nullptr, nullptr, nullptr, nullptr, nullptr, ff1);

    gemm_kernel<EPI_FF2, 3072><<<dim3(6, 64), 256, 0, stream>>>(
        ff1, wff2T, b_ff2, nullptr, nullptr, nullptr, nullptr, x1f, res, nullptr);
    ln_kernel<<<2048, 256, 0, stream>>>(res, ln2_g, ln2_b, out, nullptr);

    (void)in_sizes; (void)n_in; (void)out_size; (void)ws_size;
}

// Round 8
// 388.044 us; speedup vs baseline: 1.2028x; 1.2028x over previous
//
#include <hip/hip_runtime.h>
#include <math.h>

// EncoderBlock: B=8, N=1024, EMB=768, HEADS=8, DHEAD=96
// R8: keep R6 K-loop (BK=64, 2-barrier, swizzled, 0 conflicts — best measured).
//     (a) XCD-stripe grid swizzle: by=((id&7)<<3)|((id>>3)&7) -> each XCD owns
//         a 1024-row M-stripe; A-stripe 1.6MB stays L2-resident (R6 FETCH
//         57.7MB vs 17MB ideal = cross-XCD A streaming at HBM latency).
//     (b) GELU via sigmoid identity (erff was ~5000cy/wave — more than the
//         K-loop's MFMA time).
//     (c) QKVR weights column-permuted (n' = which*768 + hd) so `which` is
//         block-uniform: single branch, contiguous q/k/r stores, V^T stores
//         packed 8B over 4 consecutive seq positions.

typedef __bf16 bf16_t;
typedef __bf16 bf16x4 __attribute__((ext_vector_type(4)));
typedef __bf16 bf16x8 __attribute__((ext_vector_type(8)));
typedef float f32x4 __attribute__((ext_vector_type(4)));

#define EMB   768
#define HEADS 8
#define DHEAD 96
#define BATCH 8
#define SEQ   1024
#define ROWS  (BATCH * SEQ)   // 8192

__device__ __forceinline__ void load16_lds(const bf16_t* g, bf16_t* l) {
    __builtin_amdgcn_global_load_lds(
        (__attribute__((address_space(1))) unsigned int*)g,
        (__attribute__((address_space(3))) unsigned int*)l,
        16, 0, 0);
}

// ---------------------------------------------------------------- conversions

__global__ void cvt_bf16_kernel(const float* __restrict__ in, bf16_t* __restrict__ out, int n) {
    int stride = gridDim.x * blockDim.x;
    for (int i = blockIdx.x * blockDim.x + threadIdx.x; i < n; i += stride)
        out[i] = (bf16_t)in[i];
}

// in: [K][N] fp32 row-major  ->  out: [N][K] bf16 row-major (B^T for GEMMs)
__global__ void transpose_cvt_kernel(const float* __restrict__ in, bf16_t* __restrict__ out,
                                     int K, int N) {
    __shared__ float t[32][33];
    int n0 = blockIdx.x * 32, k0 = blockIdx.y * 32;
    int tx = threadIdx.x, ty0 = threadIdx.y;  // block (32,8)
#pragma unroll
    for (int i = 0; i < 4; i++) {
        int ty = ty0 + 8 * i;
        t[ty][tx] = in[(size_t)(k0 + ty) * N + n0 + tx];
    }
    __syncthreads();
#pragma unroll
    for (int i = 0; i < 4; i++) {
        int ty = ty0 + 8 * i;
        out[(size_t)(n0 + ty) * K + k0 + tx] = (bf16_t)t[tx][ty];
    }
}

// w_qkvr [768][3072] -> wqkvrT [3072][768] bf16 with COLUMN PERMUTATION:
// output row n' = which*768 + hd  <-  source column hd*4 + which.
__global__ void qkvr_transpose_kernel(const float* __restrict__ in, bf16_t* __restrict__ out) {
    __shared__ float t[32][33];
    int n0 = blockIdx.x * 32, k0 = blockIdx.y * 32;
    int tx = threadIdx.x, ty0 = threadIdx.y;  // block (32,8)
    const int which = n0 / 768, hd0 = n0 % 768;
#pragma unroll
    for (int i = 0; i < 4; i++) {
        int ty = ty0 + 8 * i;
        t[ty][tx] = in[(size_t)(k0 + ty) * 3072 + (hd0 + tx) * 4 + which];
    }
    __syncthreads();
#pragma unroll
    for (int i = 0; i < 4; i++) {
        int ty = ty0 + 8 * i;
        out[(size_t)(n0 + ty) * 768 + k0 + tx] = (bf16_t)t[tx][ty];
    }
}

// ---------------------------------------------------------------- GEMM (bf16 MFMA)
// C[M,N] = A[M,K] @ BT[N,K]^T + bias, 128x128 tile, BK=64, 256 thr, 4 waves 2x2.
// 2-barrier K-loop, global_load_lds staging, XOR-8 swizzled 16B units.
// 1D grid, XCD-stripe swizzle: id -> bx=id>>6, by=((id&7)<<3)|((id>>3)&7).

enum { EPI_QKVR = 0, EPI_PROJ = 1, EPI_GELU = 2, EPI_FF2 = 3 };

template <int EPI, int KDIM>
__global__ __launch_bounds__(256) void gemm_kernel(
    const bf16_t* __restrict__ A,    // [M,KDIM]
    const bf16_t* __restrict__ BT,   // [N,KDIM]
    const float* __restrict__ bias,  // [N] (EPI_QKVR: original qkvr order)
    bf16_t* __restrict__ qo, bf16_t* __restrict__ ko,
    bf16_t* __restrict__ vTo, bf16_t* __restrict__ ro,   // EPI_QKVR outputs
    const float* __restrict__ resid,                     // EPI_PROJ / EPI_FF2 residual
    float* __restrict__ outf,                            // EPI_PROJ / EPI_FF2 fp32 out
    bf16_t* __restrict__ outb)                           // EPI_GELU bf16 out
{
    __shared__ __align__(16) bf16_t As[128 * 64];
    __shared__ __align__(16) bf16_t Bs[128 * 64];

    const int tid  = threadIdx.x;
    const int wave = tid >> 6, lane = tid & 63;
    const int quad = lane >> 4, col16 = lane & 15;
    const int id = blockIdx.x;
    const int bx = id >> 6;
    const int by = ((id & 7) << 3) | ((id >> 3) & 7);
    const int m0 = by * 128, n0 = bx * 128;
    const int wrow = (wave >> 1) * 64, wcol = (wave & 1) * 64;

    f32x4 acc[4][4] = {};

    // staging map: 1024 16B-units per matrix; unit u -> row=u>>3, slot=u&7,
    // global k-unit j = slot ^ (row&7). LDS dst stays lane-contiguous.
    size_t ga[4], gb[4];
#pragma unroll
    for (int i = 0; i < 4; i++) {
        const int u = tid + 256 * i;
        const int rr = u >> 3, j = (u & 7) ^ (rr & 7);
        ga[i] = (size_t)(m0 + rr) * KDIM + j * 8;
        gb[i] = (size_t)(n0 + rr) * KDIM + j * 8;
    }

    for (int kk = 0; kk < KDIM / 64; kk++) {
        const int k0 = kk * 64;
        __syncthreads();  // prev iteration's LDS readers done
#pragma unroll
        for (int i = 0; i < 4; i++) {
            load16_lds(A + ga[i] + k0, As + (tid + 256 * i) * 8);
            load16_lds(BT + gb[i] + k0, Bs + (tid + 256 * i) * 8);
        }
        __syncthreads();  // drains vmcnt: tile ready
#pragma unroll
        for (int kc = 0; kc < 2; kc++) {
            bf16x8 af[4], bfr[4];
#pragma unroll
            for (int t = 0; t < 4; t++) {
                const int R = wrow + t * 16 + col16;
                af[t] = *reinterpret_cast<const bf16x8*>(As + R * 64 + (((kc * 4 + quad) ^ (R & 7)) * 8));
            }
#pragma unroll
            for (int t = 0; t < 4; t++) {
                const int R = wcol + t * 16 + col16;
                bfr[t] = *reinterpret_cast<const bf16x8*>(Bs + R * 64 + (((kc * 4 + quad) ^ (R & 7)) * 8));
            }
#pragma unroll
            for (int tr = 0; tr < 4; tr++)
#pragma unroll
                for (int tc = 0; tc < 4; tc++)
                    acc[tr][tc] = __builtin_amdgcn_mfma_f32_16x16x32_bf16(af[tr], bfr[tc], acc[tr][tc], 0, 0, 0);
        }
    }

    if (EPI == EPI_QKVR) {
        // permuted column axis: colg = which*768 + hd; which block-uniform.
        const int whichb = bx / 6;
        if (whichb == 2) {
            // V: transpose store, packed over 4 consecutive seq positions.
#pragma unroll
            for (int tr = 0; tr < 4; tr++) {
#pragma unroll
                for (int tc = 0; tc < 4; tc++) {
                    const int hd   = (bx % 6) * 128 + wcol + tc * 16 + col16;
                    const int head = hd / DHEAD, dd = hd % DHEAD;
                    const float bv = bias[hd * 4 + 2];
                    const int row0 = m0 + wrow + tr * 16 + quad * 4;
                    const int b = row0 >> 10, nn0 = row0 & 1023;
                    bf16x4 w;
#pragma unroll
                    for (int rg = 0; rg < 4; rg++) w[rg] = (bf16_t)(acc[tr][tc][rg] + bv);
                    *reinterpret_cast<bf16x4*>(
                        vTo + ((size_t)(b * HEADS + head) * DHEAD + dd) * SEQ + nn0) = w;
                }
            }
        } else {
            bf16_t* dst = (whichb == 0) ? qo : (whichb == 1) ? ko : ro;
#pragma unroll
            for (int tr = 0; tr < 4; tr++) {
#pragma unroll
                for (int tc = 0; tc < 4; tc++) {
                    const int hd   = (bx % 6) * 128 + wcol + tc * 16 + col16;
                    const int head = hd / DHEAD, dd = hd % DHEAD;
                    const float bv = bias[hd * 4 + whichb];
#pragma unroll
                    for (int rg = 0; rg < 4; rg++) {
                        const int row = m0 + wrow + tr * 16 + quad * 4 + rg;
                        const int b = row >> 10, nn = row & 1023;
                        dst[((size_t)(b * HEADS + head) * SEQ + nn) * DHEAD + dd] =
                            (bf16_t)(acc[tr][tc][rg] + bv);
                    }
                }
            }
        }
    } else {
#pragma unroll
        for (int tr = 0; tr < 4; tr++) {
#pragma unroll
            for (int tc = 0; tc < 4; tc++) {
#pragma unroll
                for (int rg = 0; rg < 4; rg++) {
                    const int row  = m0 + wrow + tr * 16 + quad * 4 + rg;
                    const int colg = n0 + wcol + tc * 16 + col16;
                    float v = acc[tr][tc][rg] + bias[colg];
                    if (EPI == EPI_PROJ || EPI == EPI_FF2) {
                        outf[(size_t)row * EMB + colg] = v + resid[(size_t)row * EMB + colg];
                    } else {  // EPI_GELU: tanh-form gelu via sigmoid (|err|<3e-3 vs erf)
                        const float z = 1.5957691216057308f * v * (1.0f + 0.044715f * v * v);
                        const float g = v / (1.0f + __expf(-z));
                        outb[(size_t)row * 3072 + colg] = (bf16_t)g;
                    }
                }
            }
        }
    }
}

// ---------------------------------------------------------------- attention
// (unchanged from R6)

__global__ __launch_bounds__(256) void attn_kernel(
    const bf16_t* __restrict__ q, const bf16_t* __restrict__ k,
    const bf16_t* __restrict__ vT, const bf16_t* __restrict__ r,
    bf16_t* __restrict__ attn_out)
{
    __shared__ __align__(16) bf16_t Ks[64 * 96];    // [key][dim]
    __shared__ __align__(16) bf16_t Vs[96 * 64];    // [feat][16B-unit swizzled by feat&7]
    __shared__ __align__(16) bf16_t P[4][16 * 72];  // wave-private P (barriers protect reuse)

    const int tid = threadIdx.x, wave = tid >> 6, lane = tid & 63;
    const int quad = lane >> 4, col = lane & 15;
    const int bh = blockIdx.x & 63, qb = blockIdx.x >> 6;
    const int n0 = qb * 64 + wave * 16;
    const bf16_t* qp = q  + (size_t)bh * SEQ * DHEAD;
    const bf16_t* kb = k  + (size_t)bh * SEQ * DHEAD;
    const bf16_t* vb = vT + (size_t)bh * DHEAD * SEQ;
    bf16_t* Pw = P[wave];

    bf16x8 qf[3];  // Q as B-operand: B[k=dim][n=q-row]
#pragma unroll
    for (int ks = 0; ks < 3; ks++)
        qf[ks] = *reinterpret_cast<const bf16x8*>(qp + (size_t)(n0 + col) * DHEAD + ks * 32 + quad * 8);

    // staging unit ids (16B units): K has 64*12=768, V has 96*8=768
    const int u0 = tid, u1 = tid + 256, u2 = tid + 512;
    const int vf0 = u0 >> 3, vp0 = (u0 & 7) ^ (vf0 & 7);
    const int vf1 = u1 >> 3, vp1 = (u1 & 7) ^ (vf1 & 7);
    const int vf2 = u2 >> 3, vp2 = (u2 & 7) ^ (vf2 & 7);

    f32x4 O[6] = {};
    float lsum = 0.f;  // per-lane partial row-sum for q-row `col`

    for (int ch = 0; ch < SEQ / 64; ch++) {
        const int kc0 = ch * 64;
        __syncthreads();  // all waves done reading Ks/Vs of previous chunk
        const bf16_t* ksrc = kb + (size_t)kc0 * DHEAD;  // 64 keys x 96 dims, contiguous
        load16_lds(ksrc + u0 * 8, Ks + u0 * 8);
        load16_lds(ksrc + u1 * 8, Ks + u1 * 8);
        load16_lds(ksrc + u2 * 8, Ks + u2 * 8);
        load16_lds(vb + (size_t)vf0 * SEQ + kc0 + vp0 * 8, Vs + u0 * 8);
        load16_lds(vb + (size_t)vf1 * SEQ + kc0 + vp1 * 8, Vs + u1 * 8);
        load16_lds(vb + (size_t)vf2 * SEQ + kc0 + vp2 * 8, Vs + u2 * 8);
        __syncthreads();  // compiler drains vmcnt before barrier: tiles ready

        f32x4 s[4] = {};
#pragma unroll
        for (int ks = 0; ks < 3; ks++) {  // K as A-operand: A[m=key][k=dim]
#pragma unroll
            for (int h = 0; h < 4; h++) {
                bf16x8 kf = *reinterpret_cast<const bf16x8*>(Ks + (h * 16 + col) * DHEAD + ks * 32 + quad * 8);
                s[h] = __builtin_amdgcn_mfma_f32_16x16x32_bf16(kf, qf[ks], s[h], 0, 0, 0);
            }
        }
        // S^T C-layout: lane holds keys h*16+quad*4+rg for q-row `col`
#pragma unroll
        for (int h = 0; h < 4; h++) {
            bf16x4 w;
#pragma unroll
            for (int rg = 0; rg < 4; rg++) {
                const float e = __expf(s[h][rg]);
                lsum += e;
                w[rg] = (bf16_t)e;
            }
            *reinterpret_cast<bf16x4*>(Pw + col * 72 + h * 16 + quad * 4) = w;
        }
        // A-operand read back: A[m=q-row=col][k=key]
        bf16x8 af0 = *reinterpret_cast<const bf16x8*>(Pw + col * 72 + quad * 8);
        bf16x8 af1 = *reinterpret_cast<const bf16x8*>(Pw + col * 72 + 32 + quad * 8);
#pragma unroll
        for (int tc = 0; tc < 6; tc++) {  // V as B-operand: B[k=key][n=feat]
            const int feat = tc * 16 + col;
            bf16x8 bv0 = *reinterpret_cast<const bf16x8*>(Vs + feat * 64 + ((quad)     ^ (col & 7)) * 8);
            bf16x8 bv1 = *reinterpret_cast<const bf16x8*>(Vs + feat * 64 + ((4 + quad) ^ (col & 7)) * 8);
            O[tc] = __builtin_amdgcn_mfma_f32_16x16x32_bf16(af0, bv0, O[tc], 0, 0, 0);
            O[tc] = __builtin_amdgcn_mfma_f32_16x16x32_bf16(af1, bv1, O[tc], 0, 0, 0);
        }
    }

    // finalize row sums: reduce over quads (lanes sharing `col`)
    lsum += __shfl_xor(lsum, 16);
    lsum += __shfl_xor(lsum, 32);

    const float inv_sqrt_emb = 0.036084391824351615f;  // 1/sqrt(768)
    const int b = bh >> 3, h = bh & 7;
#pragma unroll
    for (int rg = 0; rg < 4; rg++) {
        const int nrow = quad * 4 + rg;
        const float lr = __shfl(lsum, nrow);  // lane nrow holds q-row nrow's sum
        const float scale = inv_sqrt_emb / lr;
        const int n = n0 + nrow;
#pragma unroll
        for (int tc = 0; tc < 6; tc++) {
            const int feat = tc * 16 + col;
            const float rv = (float)r[((size_t)bh * SEQ + n) * DHEAD + feat];
            attn_out[((size_t)(b * SEQ + n)) * EMB + h * DHEAD + feat] = (bf16_t)(O[tc][rg] * scale * rv);
        }
    }
}

// ---------------------------------------------------------------- LayerNorm (row=768)

__global__ __launch_bounds__(256) void ln_kernel(
    const float* __restrict__ in, const float* __restrict__ g, const float* __restrict__ b,
    float* __restrict__ y, bf16_t* __restrict__ yb)
{
    const int row = blockIdx.x * 4 + (threadIdx.x >> 6);
    const int lane = threadIdx.x & 63;
    const float* rp = in + (size_t)row * EMB;
    float v[12];
    float sum = 0.f;
#pragma unroll
    for (int i = 0; i < 12; i++) { v[i] = rp[lane + i * 64]; sum += v[i]; }
#pragma unroll
    for (int off = 32; off; off >>= 1) sum += __shfl_xor(sum, off);
    const float mean = sum * (1.0f / 768.0f);
    float s2 = 0.f;
#pragma unroll
    for (int i = 0; i < 12; i++) { float d = v[i] - mean; s2 += d * d; }
#pragma unroll
    for (int off = 32; off; off >>= 1) s2 += __shfl_xor(s2, off);
    const float inv = rsqrtf(s2 * (1.0f / 768.0f) + 1e-5f);
#pragma unroll
    for (int i = 0; i < 12; i++) {
        const int c = lane + i * 64;
        const float o = (v[i] - mean) * inv * g[c] + b[c];
        y[(size_t)row * EMB + c] = o;
        if (yb) yb[(size_t)row * EMB + c] = (bf16_t)o;
    }
}

// ---------------------------------------------------------------- launch

extern "C" void kernel_launch(void* const* d_in, const int* in_sizes, int n_in,
                              void* d_out, int out_size, void* d_ws, size_t ws_size,
                              hipStream_t stream)
{
    const float* x      = (const float*)d_in[0];
    const float* w_qkvr = (const float*)d_in[1];
    const float* b_qkvr = (const float*)d_in[2];
    const float* w_proj = (const float*)d_in[3];
    const float* b_proj = (const float*)d_in[4];
    const float* ln1_g  = (const float*)d_in[5];
    const float* ln1_b  = (const float*)d_in[6];
    const float* w_ff1  = (const float*)d_in[7];
    const float* b_ff1  = (const float*)d_in[8];
    const float* w_ff2  = (const float*)d_in[9];
    const float* b_ff2  = (const float*)d_in[10];
    const float* ln2_g  = (const float*)d_in[11];
    const float* ln2_b  = (const float*)d_in[12];
    float* out = (float*)d_out;

    char* ws = (char*)d_ws;
    size_t off = 0;
    auto alloc = [&](size_t bytes) {
        char* p = ws + off;
        off += (bytes + 255) & ~(size_t)255;
        return (void*)p;
    };
    const size_t ACT = (size_t)ROWS * EMB;  // 6291456
    bf16_t* xb      = (bf16_t*)alloc(ACT * 2);
    bf16_t* wqkvrT  = (bf16_t*)alloc((size_t)3072 * 768 * 2);
    bf16_t* wprojT  = (bf16_t*)alloc((size_t)768 * 768 * 2);
    bf16_t* wff1T   = (bf16_t*)alloc((size_t)3072 * 768 * 2);
    bf16_t* wff2T   = (bf16_t*)alloc((size_t)768 * 3072 * 2);
    bf16_t* qbuf    = (bf16_t*)alloc(ACT * 2);
    bf16_t* kbuf    = (bf16_t*)alloc(ACT * 2);
    bf16_t* vTbuf   = (bf16_t*)alloc(ACT * 2);
    bf16_t* rbuf    = (bf16_t*)alloc(ACT * 2);
    bf16_t* attn_o  = (bf16_t*)alloc(ACT * 2);
    float*  x1f     = (float*)alloc(ACT * 4);
    bf16_t* x1b     = (bf16_t*)alloc(ACT * 2);
    bf16_t* ff1     = (bf16_t*)alloc((size_t)ROWS * 3072 * 2);
    float*  res     = out;  // d_out doubles as fp32 residual scratch

    dim3 tb32(32, 8);

    cvt_bf16_kernel<<<2048, 256, 0, stream>>>(x, xb, (int)ACT);
    qkvr_transpose_kernel<<<dim3(3072 / 32, 768 / 32), tb32, 0, stream>>>(w_qkvr, wqkvrT);
    transpose_cvt_kernel<<<dim3(768 / 32, 768 / 32), tb32, 0, stream>>>(w_proj, wprojT, 768, 768);
    transpose_cvt_kernel<<<dim3(3072 / 32, 768 / 32), tb32, 0, stream>>>(w_ff1, wff1T, 768, 3072);
    transpose_cvt_kernel<<<dim3(768 / 32, 3072 / 32), tb32, 0, stream>>>(w_ff2, wff2T, 3072, 768);

    gemm_kernel<EPI_QKVR, 768><<<24 * 64, 256, 0, stream>>>(
        xb, wqkvrT, b_qkvr, qbuf, kbuf, vTbuf, rbuf, nullptr, nullptr, nullptr);

    attn_kernel<<<dim3(SEQ / 64 * BATCH * HEADS), 256, 0, stream>>>(qbuf, kbuf, vTbuf, rbuf, attn_o);

    gemm_kernel<EPI_PROJ, 768><<<6 * 64, 256, 0, stream>>>(
        attn_o, wprojT, b_proj, nullptr, nullptr, nullptr, nullptr, x, res, nullptr);
    ln_kernel<<<2048, 256, 0, stream>>>(res, ln1_g, ln1_b, x1f, x1b);

    gemm_kernel<EPI_GELU, 768><<<24 * 64, 256, 0, stream>>>(
        x1b, wff1T, b_ff1, nullptr, nullptr, nullptr, nullptr, nullptr, nullptr, ff1);

    gemm_kernel<EPI_FF2, 3072><<<6 * 64, 256, 0, stream>>>(
        ff1, wff2T, b_ff2, nullptr, nullptr, nullptr, nullptr, x1f, res, nullptr);
    ln_kernel<<<2048, 256, 0, stream>>>(res, ln2_g, ln2_b, out, nullptr);

    (void)in_sizes; (void)n_in; (void)out_size; (void)ws_size;
}